// Round 10
// baseline (59.490 us; speedup 1.0000x reference)
//
#include <hip/hip_runtime.h>

// x:(8,64,56,56) f32 -> out:(8,64,49,3136) f32
// out[n,c,ki*7+kj, oh*56+ow] = x[n,c,oh,ow] - (in-bounds ? x[n,c,oh+ki-3,ow+kj-3] : 0)
//
// R9 = R4 verbatim (measured optimum, 55.4 us = ~5.7 TB/s effective).
// One block per (n,c) plane (512 blocks = 2/CU). Input plane staged in LDS
// with zero halo (no bounds checks); block writes its 614 KB output region
// fully sequentially (kk-major). R5-R8 restructures (b128 windows, finer
// blocks, fused halo zero, distributed tails) all measured neutral/worse:
// the op is at the mixed-stream HBM write-drain ceiling (~84% of fill's
// pure-write rate).

constexpr int H_ = 56, W_ = 56;
constexpr int KK_  = 49;
constexpr int OHW_ = 3136;              // 56*56
constexpr int PP_  = 63;                // padded LDS pitch (floats)
constexpr int PR_  = 62;                // padded rows: -3..58
constexpr int NC_  = 512;               // 8*64 planes
constexpr int LDSN_ = PR_ * PP_;        // 3906 floats = 15.6 KB

typedef float f32x4 __attribute__((ext_vector_type(4)));

__global__ __launch_bounds__(256)
void san_kernel(const float* __restrict__ x, float* __restrict__ out) {
    __shared__ float lds[LDSN_];
    const int nc = blockIdx.x;
    const int t  = threadIdx.x;

    // 1) zero padded plane (halo stays zero -> OOB neighbors read 0)
    #pragma unroll
    for (int i = 0; i < 16; ++i) {
        int j = t + 256 * i;
        if (j < LDSN_) lds[j] = 0.0f;
    }
    __syncthreads();

    const float* plane = x + (size_t)nc * OHW_;

    // 2) stage interior; keep each slot's center f4 + LDS base in registers.
    //    slot S covers f4-index e4 = t + 256*S of the plane (784 f4 total).
    f32x4 cen0{}, cen1{}, cen2{}, cen3{};
    int ab0 = 0, ab1 = 0, ab2 = 0, ab3 = 0;
    const bool has3 = (t < 16);          // 784 - 3*256 = 16

#define STAGE(S, CEN, AB)                                           \
    {                                                               \
        int e4 = t + 256 * (S);                                     \
        int oh = e4 / 14, o4 = e4 - oh * 14;                        \
        CEN = *reinterpret_cast<const f32x4*>(plane + e4 * 4);      \
        int lb = (oh + 3) * PP_ + o4 * 4 + 3;                       \
        lds[lb + 0] = CEN[0]; lds[lb + 1] = CEN[1];                 \
        lds[lb + 2] = CEN[2]; lds[lb + 3] = CEN[3];                 \
        AB = oh * PP_ + o4 * 4;                                     \
    }
    STAGE(0, cen0, ab0)
    STAGE(1, cen1, ab1)
    STAGE(2, cen2, ab2)
    if (has3) STAGE(3, cen3, ab3)
#undef STAGE
    __syncthreads();

    // 3) kk-major sweep: block writes its 49*12544 B region front-to-back.
    //    neighbor(padded) = ab + ki*PP_ + kj + tt  (compile-time imm offsets)
    float* ob  = out + (size_t)nc * (KK_ * OHW_);
    float* op0 = ob + (size_t)(t      ) * 4;
    float* op1 = ob + (size_t)(t + 256) * 4;
    float* op2 = ob + (size_t)(t + 512) * 4;

    #pragma unroll
    for (int ki = 0; ki < 7; ++ki) {
        #pragma unroll
        for (int kj = 0; kj < 7; ++kj) {
            const int off = ki * PP_ + kj;
            f32x4 r0, r1, r2;
            #pragma unroll
            for (int tt = 0; tt < 4; ++tt) {
                r0[tt] = cen0[tt] - lds[ab0 + off + tt];
                r1[tt] = cen1[tt] - lds[ab1 + off + tt];
                r2[tt] = cen2[tt] - lds[ab2 + off + tt];
            }
            *reinterpret_cast<f32x4*>(op0) = r0;  op0 += OHW_;
            *reinterpret_cast<f32x4*>(op1) = r1;  op1 += OHW_;
            *reinterpret_cast<f32x4*>(op2) = r2;  op2 += OHW_;
        }
    }

    // 4) tail slot (16 threads): e4 = 768 + t
    if (has3) {
        float* op3 = ob + (size_t)(t + 768) * 4;
        for (int ki = 0; ki < 7; ++ki) {
            for (int kj = 0; kj < 7; ++kj) {
                int off = ki * PP_ + kj;
                f32x4 r;
                #pragma unroll
                for (int tt = 0; tt < 4; ++tt)
                    r[tt] = cen3[tt] - lds[ab3 + off + tt];
                *reinterpret_cast<f32x4*>(op3) = r;  op3 += OHW_;
            }
        }
    }
}

extern "C" void kernel_launch(void* const* d_in, const int* in_sizes, int n_in,
                              void* d_out, int out_size, void* d_ws, size_t ws_size,
                              hipStream_t stream) {
    const float* x = (const float*)d_in[0];
    float* out = (float*)d_out;
    san_kernel<<<NC_, 256, 0, stream>>>(x, out);
}